// Round 1
// baseline (100.953 us; speedup 1.0000x reference)
//
#include <hip/hip_runtime.h>
#include <math.h>

#define BS 2
#define C  32
#define H  256
#define W  256
#define HW (H * W)
#define PS 5

// f32(pi), matching JAX's rounding of np.pi to float32
#define PI_F 3.14159274101257324e+00f

// ---------------------------------------------------------------------------
// Kernel 1: transpose source (b, c, h, w) -> (b, h*w, c) so each gather point
// is a contiguous 128B chunk. LDS-tiled, conflict-free, coalesced both sides.
// ---------------------------------------------------------------------------
__global__ __launch_bounds__(256) void transpose_chw_to_hwc(
    const float* __restrict__ src, float* __restrict__ dst) {
    __shared__ float lds[C][64 + 1];   // +1 pad: (65c+p)%32 = (c+p)%32, 2-way max (free)

    const int block = blockIdx.x;                  // BS * HW/64 blocks
    const int b     = block / (HW / 64);
    const int p0    = (block % (HW / 64)) * 64;    // 64 consecutive pixels
    const int tid   = threadIdx.x;
    const int px    = tid & 63;                    // pixel within tile
    const int g     = tid >> 6;                    // 0..3

    const float* sb = src + (size_t)b * C * HW;
    #pragma unroll
    for (int k = 0; k < 8; ++k) {
        const int ch = k * 4 + g;                  // covers 0..31
        lds[ch][px] = sb[(size_t)ch * HW + p0 + px];   // 256B coalesced per 64 lanes
    }
    __syncthreads();

    float* db = dst + ((size_t)b * HW + p0) * C;   // 8KB contiguous region
    #pragma unroll
    for (int k = 0; k < 8; ++k) {
        const int e  = k * 256 + tid;              // 0..2047, consecutive across tid
        const int pl = e >> 5;
        const int ch = e & 31;
        db[e] = lds[ch][pl];                       // 1KB coalesced stores
    }
}

// ---------------------------------------------------------------------------
// Kernel 2: gather + 5x5 patch sum. 8 lanes per pixel; lane k owns channels
// [4k, 4k+4). One float4 load per patch point -> 8 lanes x 16B = the pixel's
// full 128B chunk; a wave (8 pixels) issues perfectly-packed transactions.
// ---------------------------------------------------------------------------
__global__ __launch_bounds__(256) void gather_sum_t(
    const float* __restrict__ tsrc,   // (b, h*w, c)
    const float* __restrict__ nnf,    // (b, 3, h, w)
    float* __restrict__ out) {        // (b, c, h, w)
    const unsigned gid = blockIdx.x * 256u + threadIdx.x;
    const unsigned pix = gid >> 3;           // global pixel
    const unsigned k   = gid & 7u;           // float4 chunk (channels 4k..4k+3)
    const unsigned b   = pix >> 16;          // HW == 65536
    const unsigned p   = pix & 0xFFFFu;

    const float* nb = nnf + (size_t)b * 3 * HW;
    const float ci = nb[p];                  // row coord
    const float cj = nb[HW + p];             // col coord
    const float a  = nb[2 * HW + p];         // angle in [0,1)

    // Match XLA: sin(a*pi_f32), cos(a*pi_f32) via ocml; block FMA contraction
    const float arg = __fmul_rn(a, PI_F);
    const float s = sinf(arg);
    const float c = cosf(arg);

    float4 acc = make_float4(0.f, 0.f, 0.f, 0.f);
    const float4* tb = (const float4*)(tsrc + (size_t)b * HW * C) + k;

    #pragma unroll
    for (int i = 0; i < PS; ++i) {
        #pragma unroll
        for (int j = 0; j < PS; ++j) {
            const float fi = (float)(i - 2);     // pi_j = xx = i-2
            const float fj = (float)(j - 2);     // pi_i = yy = j-2
            // iR = (j-2)*s - (i-2)*c ; jR = (j-2)*c - (i-2)*s  (no contraction)
            const float iR = __fsub_rn(__fmul_rn(fj, s), __fmul_rn(fi, c));
            const float jR = __fsub_rn(__fmul_rn(fj, c), __fmul_rn(fi, s));
            float pr = __fadd_rn(ci, iR);
            float pc = __fadd_rn(cj, jR);
            pr = fminf(fmaxf(pr, 0.0f), (float)(H - 1));
            pc = fminf(fmaxf(pc, 0.0f), (float)(W - 1));
            const int row = (int)pr;             // trunc == floor (non-negative)
            const int col = (int)pc;
            const int idx = (row << 8) + col;
            const float4 v = tb[(size_t)idx * (C / 4)];
            acc.x += v.x; acc.y += v.y; acc.z += v.z; acc.w += v.w;
        }
    }

    float* ob = out + ((size_t)b * C + k * 4) * HW + p;
    ob[0]          = acc.x;
    ob[HW]         = acc.y;
    ob[2 * (size_t)HW] = acc.z;
    ob[3 * (size_t)HW] = acc.w;
}

// ---------------------------------------------------------------------------
// Fallback (only if ws too small): gather directly from (b,c,h,w) layout.
// ---------------------------------------------------------------------------
__global__ __launch_bounds__(256) void gather_sum_direct(
    const float* __restrict__ src,    // (b, c, h, w)
    const float* __restrict__ nnf,
    float* __restrict__ out) {
    const unsigned gid = blockIdx.x * 256u + threadIdx.x;
    const unsigned pix = gid >> 3;
    const unsigned k   = gid & 7u;
    const unsigned b   = pix >> 16;
    const unsigned p   = pix & 0xFFFFu;

    const float* nb = nnf + (size_t)b * 3 * HW;
    const float ci = nb[p];
    const float cj = nb[HW + p];
    const float a  = nb[2 * HW + p];

    const float arg = __fmul_rn(a, PI_F);
    const float s = sinf(arg);
    const float c = cosf(arg);

    float4 acc = make_float4(0.f, 0.f, 0.f, 0.f);
    const float* sb = src + ((size_t)b * C + k * 4) * HW;

    #pragma unroll
    for (int i = 0; i < PS; ++i) {
        #pragma unroll
        for (int j = 0; j < PS; ++j) {
            const float fi = (float)(i - 2);
            const float fj = (float)(j - 2);
            const float iR = __fsub_rn(__fmul_rn(fj, s), __fmul_rn(fi, c));
            const float jR = __fsub_rn(__fmul_rn(fj, c), __fmul_rn(fi, s));
            float pr = __fadd_rn(ci, iR);
            float pc = __fadd_rn(cj, jR);
            pr = fminf(fmaxf(pr, 0.0f), (float)(H - 1));
            pc = fminf(fmaxf(pc, 0.0f), (float)(W - 1));
            const int idx = (((int)pr) << 8) + (int)pc;
            acc.x += sb[idx];
            acc.y += sb[HW + idx];
            acc.z += sb[2 * HW + idx];
            acc.w += sb[3 * HW + idx];
        }
    }

    float* ob = out + ((size_t)b * C + k * 4) * HW + p;
    ob[0]          = acc.x;
    ob[HW]         = acc.y;
    ob[2 * (size_t)HW] = acc.z;
    ob[3 * (size_t)HW] = acc.w;
}

extern "C" void kernel_launch(void* const* d_in, const int* in_sizes, int n_in,
                              void* d_out, int out_size, void* d_ws, size_t ws_size,
                              hipStream_t stream) {
    const float* src = (const float*)d_in[0];   // (2, 32, 256, 256) f32
    const float* nnf = (const float*)d_in[1];   // (2, 3, 256, 256) f32
    float* out = (float*)d_out;                 // (2, 32, 256, 256) f32

    const size_t need = (size_t)BS * HW * C * sizeof(float);   // 16.8 MB
    if (ws_size >= need) {
        float* tsrc = (float*)d_ws;
        transpose_chw_to_hwc<<<BS * (HW / 64), 256, 0, stream>>>(src, tsrc);
        gather_sum_t<<<(BS * HW * 8) / 256, 256, 0, stream>>>(tsrc, nnf, out);
    } else {
        gather_sum_direct<<<(BS * HW * 8) / 256, 256, 0, stream>>>(src, nnf, out);
    }
}